// Round 9
// baseline (197.553 us; speedup 1.0000x reference)
//
#include <hip/hip_runtime.h>
#include <math.h>

#define B_   8
#define P_   196
#define L_   80
#define DIM1 2048
#define DIM2 300
#define ATT  1024

typedef __attribute__((ext_vector_type(8))) short short8_t;
typedef __attribute__((ext_vector_type(4))) float f32x4_t;

__device__ inline unsigned short f2bf(float f) {
    unsigned int u = __float_as_uint(f);
    u += 0x7fff + ((u >> 16) & 1);          // RNE
    return (unsigned short)(u >> 16);
}
__device__ inline float bf2f(unsigned short h) {
    return __uint_as_float(((unsigned int)h) << 16);
}

// ---------------------------------------------------------------- prep: w = Wh@Wt; bias2 = bh.Wt + bt + sum(w)  (atomic accumulate)
__global__ __launch_bounds__(256) void prep_w(const float* __restrict__ Wh,
                                              const float* __restrict__ bh,
                                              const float* __restrict__ Wt,
                                              const float* __restrict__ btp,
                                              float* __restrict__ w,
                                              float* __restrict__ biasp) {
    const int tid  = threadIdx.x;
    const int lane = tid & 63;
    const int row  = blockIdx.x * 4 + (tid >> 6);
    const float* src = (row < ATT) ? (Wh + (size_t)row * ATT) : bh;
    if (row <= ATT) {
        float acc = 0.0f;
#pragma unroll
        for (int it = 0; it < ATT / 256; ++it) {
            const int i = it * 256 + lane * 4;
            const float4 a = *reinterpret_cast<const float4*>(src + i);
            const float4 b = *reinterpret_cast<const float4*>(Wt + i);
            acc = fmaf(a.x, b.x, acc);
            acc = fmaf(a.y, b.y, acc);
            acc = fmaf(a.z, b.z, acc);
            acc = fmaf(a.w, b.w, acc);
        }
#pragma unroll
        for (int o = 32; o >= 1; o >>= 1) acc += __shfl_xor(acc, o);
        if (lane == 0) {
            if (row < ATT) {
                w[row] = acc;
                atomicAdd(&biasp[1], acc);          // sum(w) part of bias2
            } else {
                atomicAdd(&biasp[1], acc + btp[0]); // bh.Wt + bt part
            }
        }
    }
}

// ---------------------------------------------------------------- transpose+cast both weights in one launch
// W1: in[2048][1024] -> out[1024][2048]; W2: in[300][1024] -> out[1024][320] (zero-pad k)
__global__ __launch_bounds__(256) void tcast_all(const float* __restrict__ W1,
                                                 const float* __restrict__ W2,
                                                 unsigned short* __restrict__ W1T,
                                                 unsigned short* __restrict__ W2T) {
    __shared__ unsigned short tile[32][34];
    int id = blockIdx.x;
    const float* in;
    unsigned short* out;
    int Ksrc, Kpad, k0, n0;
    if (id < 2048) {                       // W1: 64 k-blocks x 32 n-blocks
        in = W1; out = W1T; Ksrc = DIM1; Kpad = DIM1;
        k0 = (id & 63) * 32; n0 = (id >> 6) * 32;
    } else {                               // W2: 10 k-blocks x 32 n-blocks
        id -= 2048;
        in = W2; out = W2T; Ksrc = DIM2; Kpad = 320;
        k0 = (id % 10) * 32; n0 = (id / 10) * 32;
    }
    const int tx = threadIdx.x & 31, ty = threadIdx.x >> 5;   // 32 x 8
#pragma unroll
    for (int i = 0; i < 4; ++i) {
        const int r = k0 + ty + i * 8;
        const float v = (r < Ksrc) ? in[(size_t)r * 1024 + n0 + tx] : 0.f;
        tile[ty + i * 8][tx] = f2bf(v);
    }
    __syncthreads();
#pragma unroll
    for (int i = 0; i < 4; ++i) {
        const int n = ty + i * 8;
        out[(size_t)(n0 + n) * Kpad + k0 + tx] = tile[tx][n];
    }
}

// ---------------------------------------------------------------- bf16 MFMA GEMM, pipelined
// 64x64 tile, BK=64, 4 waves (32x32 each), double-buffered LDS, one barrier
// per K-step. LDS rows 128 B pitch, XOR swizzle byte^=((row&7)<<4).
template<int KSRC, int KPAD>
__global__ __launch_bounds__(256) void gemm_bf16(const float* __restrict__ Af,
                                                 const unsigned short* __restrict__ Bt,
                                                 unsigned short* __restrict__ C,
                                                 int M) {
    constexpr int NT = KPAD / 64;
    __shared__ __align__(16) char smem[32768];   // [buf][A 8K | B 8K]
    const int tid  = threadIdx.x;
    const int lane = tid & 63;
    const int wave = tid >> 6;
    const int wm = (wave >> 1) * 32;
    const int wn = (wave & 1) * 32;
    const int m0 = blockIdx.y * 64;
    const int n0 = blockIdx.x * 64;

    const int row = tid >> 2;            // 0..63 staging row
    const int kc  = (tid & 3) * 16;      // k element offset within BK
    const int swz = (row & 7) << 4;
    const int sb  = row * 128 + kc * 2;  // staging byte base (pre-XOR)
    const int gm  = m0 + row;

    float4   ra[4];                      // 16 f32 of A
    short8_t rb[2];                      // 16 bf16 of B

    auto LOAD = [&](int t) {
        const int k0 = t * 64;
        if (gm < M && k0 + 64 <= KSRC) {
            const float* ap = Af + (size_t)gm * KSRC + k0 + kc;
            ra[0] = *reinterpret_cast<const float4*>(ap);
            ra[1] = *reinterpret_cast<const float4*>(ap + 4);
            ra[2] = *reinterpret_cast<const float4*>(ap + 8);
            ra[3] = *reinterpret_cast<const float4*>(ap + 12);
        } else {
            float* rf = reinterpret_cast<float*>(ra);
#pragma unroll
            for (int j = 0; j < 16; ++j) {
                const int k = k0 + kc + j;
                rf[j] = (gm < M && k < KSRC) ? Af[(size_t)gm * KSRC + k] : 0.f;
            }
        }
        const unsigned short* bp = Bt + (size_t)(n0 + row) * KPAD + k0 + kc;
        rb[0] = *reinterpret_cast<const short8_t*>(bp);
        rb[1] = *reinterpret_cast<const short8_t*>(bp + 8);
    };

    auto WRITE = [&](int buf) {
        char* smA = smem + buf * 16384;
        char* smB = smA + 8192;
        const float* rf = reinterpret_cast<const float*>(ra);
        short8_t h0, h1;
#pragma unroll
        for (int j = 0; j < 8; ++j) h0[j] = (short)f2bf(rf[j]);
#pragma unroll
        for (int j = 0; j < 8; ++j) h1[j] = (short)f2bf(rf[8 + j]);
        *reinterpret_cast<short8_t*>(smA + ((sb)      ^ swz)) = h0;
        *reinterpret_cast<short8_t*>(smA + ((sb + 16) ^ swz)) = h1;
        *reinterpret_cast<short8_t*>(smB + ((sb)      ^ swz)) = rb[0];
        *reinterpret_cast<short8_t*>(smB + ((sb + 16) ^ swz)) = rb[1];
    };

    f32x4_t acc[2][2] = {};
    const int fr_col = (lane >> 4) << 4;   // frag k-group byte offset
    const int fl     = lane & 15;

    LOAD(0);
#pragma unroll 2
    for (int t = 0; t < NT; ++t) {
        const int buf = t & 1;
        WRITE(buf);                        // vmcnt drain for tile t happens here
        __syncthreads();
        if (t + 1 < NT) LOAD(t + 1);       // issue next tile, no wait
        const char* smA = smem + buf * 16384;
        const char* smB = smA + 8192;
#pragma unroll
        for (int kk = 0; kk < 2; ++kk) {
            short8_t af[2], bf[2];
#pragma unroll
            for (int i = 0; i < 2; ++i) {
                const int r = wm + i * 16 + fl;
                af[i] = *reinterpret_cast<const short8_t*>(
                    smA + ((r * 128 + kk * 64 + fr_col) ^ ((r & 7) << 4)));
            }
#pragma unroll
            for (int j = 0; j < 2; ++j) {
                const int r = wn + j * 16 + fl;
                bf[j] = *reinterpret_cast<const short8_t*>(
                    smB + ((r * 128 + kk * 64 + fr_col) ^ ((r & 7) << 4)));
            }
#pragma unroll
            for (int i = 0; i < 2; ++i)
#pragma unroll
                for (int j = 0; j < 2; ++j)
                    acc[i][j] = __builtin_amdgcn_mfma_f32_16x16x32_bf16(af[i], bf[j], acc[i][j], 0, 0, 0);
        }
        __syncthreads();
    }

    // epilogue: C/D layout col=lane&15, row=(lane>>4)*4+q
#pragma unroll
    for (int i = 0; i < 2; ++i) {
        const int gmb = m0 + wm + i * 16 + ((lane >> 4) << 2);
#pragma unroll
        for (int j = 0; j < 2; ++j) {
            const int gn = n0 + wn + j * 16 + fl;
#pragma unroll
            for (int q = 0; q < 4; ++q) {
                const int gmq = gmb + q;
                if (gmq < M) C[(size_t)gmq * 1024 + gn] = f2bf(acc[i][j][q]);
            }
        }
    }
}

// ---------------------------------------------------------------- score (p-split x4)
// score = bias2 - 2 * sum_a w[a] * rcp(exp2(C * a1 * a2) + 1),  C = 2*log2(e)
// Packed bf16->f32: each u32 holds 2 bf16; lo = u<<16, hi = u&0xffff0000 —
// 1 VALU/elem conversion (vs compiler's per-short extract chains).
__global__ __launch_bounds__(256) void score_part(const unsigned short* __restrict__ a1b,
                                                  const unsigned short* __restrict__ a2b,
                                                  const float* __restrict__ w,
                                                  const float* __restrict__ biasp,
                                                  float* __restrict__ scb) {
    __shared__ float2 aw[ATT];
    const int tid  = threadIdx.x;
    const int lane = tid & 63;
    const int wave = tid >> 6;
    const int b    = blockIdx.x & 7;      // batch -> XCD (L2 residency of a1 slice)
    const int rest = blockIdx.x >> 3;     // 0..319
    const int l    = rest >> 2;
    const int qtr  = rest & 3;
    const float bias2 = biasp[1];

    const unsigned short* a2p = a2b + (size_t)(b * L_ + l) * ATT;
    for (int i = tid; i < ATT; i += 256) {
        const float a2v = bf2f(a2p[i]);
        const int li = i & 511;
        const int phi = (i & ~511) | (((li & 7) << 6) + (li >> 3));
        aw[phi] = make_float2(a2v * 2.885390082f, w[i]);   // 2*log2(e)
    }
    __syncthreads();

    const int base = qtr * 49;
    float* scp = scb + (size_t)(b * L_ + l) * P_;

    for (int g = wave; g < 13; g += 4) {          // 13 groups of 4 rows (last partial)
        const int p0 = base + g * 4;
        int r[4];
#pragma unroll
        for (int q = 0; q < 4; ++q) r[q] = min(p0 + q, P_ - 1);
        float acc[4] = {0.f, 0.f, 0.f, 0.f};
#pragma unroll
        for (int it = 0; it < 2; ++it) {
            uint4 v[4];
#pragma unroll
            for (int q = 0; q < 4; ++q)
                v[q] = *reinterpret_cast<const uint4*>(
                    a1b + (size_t)(b * P_ + r[q]) * ATT + it * 512 + lane * 8);
#pragma unroll
            for (int h = 0; h < 4; ++h) {         // u32 pair index (elems 2h, 2h+1)
                const float2 c0 = aw[it * 512 + (2 * h + 0) * 64 + lane];
                const float2 c1 = aw[it * 512 + (2 * h + 1) * 64 + lane];
#pragma unroll
                for (int q = 0; q < 4; ++q) {
                    const unsigned int u = (&v[q].x)[h];
                    const float flo = __uint_as_float(u << 16);
                    const float fhi = __uint_as_float(u & 0xffff0000u);
                    const float elo = __builtin_amdgcn_exp2f(flo * c0.x);
                    acc[q] = fmaf(c0.y, __builtin_amdgcn_rcpf(elo + 1.0f), acc[q]);
                    const float ehi = __builtin_amdgcn_exp2f(fhi * c1.x);
                    acc[q] = fmaf(c1.y, __builtin_amdgcn_rcpf(ehi + 1.0f), acc[q]);
                }
            }
        }
#pragma unroll
        for (int o = 32; o >= 1; o >>= 1) {
#pragma unroll
            for (int q = 0; q < 4; ++q) acc[q] += __shfl_xor(acc[q], o);
        }
        if (lane < 4) {
            const int p = p0 + lane;
            if (p < base + 49) scp[p] = bias2 - 2.0f * acc[lane];
        }
    }
}

// ---------------------------------------------------------------- fused softmax + label_repr
// 1D grid 640: b=id&7 (XCD pin: batch's 1.6MB x1 slice L2-resident),
// dtile=(id>>3)&3 (512 d-cols), lg=id>>5 (4 l-rows). Each block softmaxes its
// 4 score rows in-register (wave w owns row l0+w), stages alpha^T in LDS,
// then GEMVs. dtile==0 blocks also write alpha to global.
__global__ __launch_bounds__(256) void label_fused(const float* __restrict__ scb,
                                                   const float* __restrict__ x1,
                                                   float* __restrict__ alpha,
                                                   float* __restrict__ out) {
    __shared__ float al[P_][4];
    const int tid  = threadIdx.x;
    const int lane = tid & 63;
    const int wave = tid >> 6;
    const int id   = blockIdx.x;
    const int b    = id & 7;
    const int rest = id >> 3;           // 0..79
    const int dtile = rest & 3;
    const int l0    = (rest >> 2) * 4;  // 0..76
    const int d0    = dtile * 512;
    const int row   = b * L_ + l0 + wave;

    // --- softmax of row (one wave per l-row)
    const float* sp = scb + (size_t)row * P_;
    float v[4];
#pragma unroll
    for (int k = 0; k < 4; ++k) {
        const int p = lane + k * 64;
        v[k] = (p < P_) ? sp[p] : -INFINITY;
    }
    float m = fmaxf(fmaxf(v[0], v[1]), fmaxf(v[2], v[3]));
#pragma unroll
    for (int o = 32; o >= 1; o >>= 1) m = fmaxf(m, __shfl_xor(m, o));
    float e[4];
    float s = 0.f;
#pragma unroll
    for (int k = 0; k < 4; ++k) {
        const int p = lane + k * 64;
        e[k] = (p < P_) ? __expf(v[k] - m) : 0.f;
        s += e[k];
    }
#pragma unroll
    for (int o = 32; o >= 1; o >>= 1) s += __shfl_xor(s, o);
    const float inv = 1.0f / s;
    float* ap = alpha + (size_t)row * P_;
#pragma unroll
    for (int k = 0; k < 4; ++k) {
        const int p = lane + k * 64;
        if (p < P_) {
            const float a = e[k] * inv;
            al[p][wave] = a;
            if (dtile == 0) ap[p] = a;
        }
    }
    __syncthreads();

    // --- GEMV: out[b, l0..l0+3, d0..d0+511] = alpha @ x1
    const int d = d0 + tid * 2;
    float acc[4][2] = {};
    for (int p = 0; p < P_; ++p) {
        const float2 x = *reinterpret_cast<const float2*>(x1 + ((size_t)(b * P_ + p)) * DIM1 + d);
        const float4 a4 = *reinterpret_cast<const float4*>(&al[p][0]);
        acc[0][0] = fmaf(a4.x, x.x, acc[0][0]);
        acc[0][1] = fmaf(a4.x, x.y, acc[0][1]);
        acc[1][0] = fmaf(a4.y, x.x, acc[1][0]);
        acc[1][1] = fmaf(a4.y, x.y, acc[1][1]);
        acc[2][0] = fmaf(a4.z, x.x, acc[2][0]);
        acc[2][1] = fmaf(a4.z, x.y, acc[2][1]);
        acc[3][0] = fmaf(a4.w, x.x, acc[3][0]);
        acc[3][1] = fmaf(a4.w, x.y, acc[3][1]);
    }
#pragma unroll
    for (int l = 0; l < 4; ++l) {
        float* op = out + ((size_t)(b * L_ + l0 + l)) * DIM1 + d;
        *reinterpret_cast<float2*>(op) = make_float2(acc[l][0], acc[l][1]);
    }
}

// ---------------------------------------------------------------- launch
extern "C" void kernel_launch(void* const* d_in, const int* in_sizes, int n_in,
                              void* d_out, int out_size, void* d_ws, size_t ws_size,
                              hipStream_t stream) {
    const float* x1 = (const float*)d_in[0];
    const float* x2 = (const float*)d_in[1];
    const float* W1 = (const float*)d_in[2];
    const float* W2 = (const float*)d_in[3];
    const float* Wh = (const float*)d_in[4];
    const float* bh = (const float*)d_in[5];
    const float* Wt = (const float*)d_in[6];
    const float* bt = (const float*)d_in[7];

    float* out       = (float*)d_out;
    float* label_out = out;                                  // B*L*DIM1
    float* alpha_out = out + (size_t)B_ * L_ * DIM1;         // B*L*P

    // workspace layout (ushort offsets); a2b aliases W1T (dead after a1 gemm)
    unsigned short* usw = (unsigned short*)d_ws;
    unsigned short* W1T = usw;                         // 1024*2048 = 2097152
    unsigned short* a2b = usw;                         // 640*1024  (aliases W1T)
    unsigned short* W2T = usw + 2097152;               // 1024*320  = 327680
    unsigned short* a1b = usw + 2424832;               // 1568*1024 = 1605632
    float* wv    = (float*)(usw + 4030464);            // 1024
    float* biasv = wv + ATT;                           // 2
    float* scb   = wv + 1028;                          // 640*196 raw scores

    hipMemsetAsync(biasv, 0, 2 * sizeof(float), stream);

    prep_w<<<ATT / 4 + 1, 256, 0, stream>>>(Wh, bh, Wt, bt, wv, biasv);

    tcast_all<<<2048 + 320, 256, 0, stream>>>(W1, W2, W1T, W2T);

    gemm_bf16<DIM1, DIM1><<<dim3(16, 25), 256, 0, stream>>>(x1, W1T, a1b, B_ * P_);
    gemm_bf16<DIM2, 320><<<dim3(16, 10), 256, 0, stream>>>(x2, W2T, a2b, B_ * L_);

    score_part<<<B_ * L_ * 4, 256, 0, stream>>>(a1b, a2b, wv, biasv, scb);

    label_fused<<<B_ * L_ * 4 / 4, 256, 0, stream>>>(scb, x1, alpha_out, label_out);
}

// Round 10
// 194.967 us; speedup vs baseline: 1.0133x; 1.0133x over previous
//
#include <hip/hip_runtime.h>
#include <math.h>

#define B_   8
#define P_   196
#define L_   80
#define DIM1 2048
#define DIM2 300
#define ATT  1024

typedef __attribute__((ext_vector_type(8))) short short8_t;
typedef __attribute__((ext_vector_type(4))) float f32x4_t;

__device__ inline unsigned short f2bf(float f) {
    unsigned int u = __float_as_uint(f);
    u += 0x7fff + ((u >> 16) & 1);          // RNE
    return (unsigned short)(u >> 16);
}
__device__ inline float bf2f(unsigned short h) {
    return __uint_as_float(((unsigned int)h) << 16);
}

// ---------------------------------------------------------------- prep: w = Wh@Wt; bias2 = bh.Wt + bt + sum(w)  (atomic accumulate)
__global__ __launch_bounds__(256) void prep_w(const float* __restrict__ Wh,
                                              const float* __restrict__ bh,
                                              const float* __restrict__ Wt,
                                              const float* __restrict__ btp,
                                              float* __restrict__ w,
                                              float* __restrict__ biasp) {
    const int tid  = threadIdx.x;
    const int lane = tid & 63;
    const int row  = blockIdx.x * 4 + (tid >> 6);
    const float* src = (row < ATT) ? (Wh + (size_t)row * ATT) : bh;
    if (row <= ATT) {
        float acc = 0.0f;
#pragma unroll
        for (int it = 0; it < ATT / 256; ++it) {
            const int i = it * 256 + lane * 4;
            const float4 a = *reinterpret_cast<const float4*>(src + i);
            const float4 b = *reinterpret_cast<const float4*>(Wt + i);
            acc = fmaf(a.x, b.x, acc);
            acc = fmaf(a.y, b.y, acc);
            acc = fmaf(a.z, b.z, acc);
            acc = fmaf(a.w, b.w, acc);
        }
#pragma unroll
        for (int o = 32; o >= 1; o >>= 1) acc += __shfl_xor(acc, o);
        if (lane == 0) {
            if (row < ATT) {
                w[row] = acc;
                atomicAdd(&biasp[1], acc);          // sum(w) part of bias2
            } else {
                atomicAdd(&biasp[1], acc + btp[0]); // bh.Wt + bt part
            }
        }
    }
}

// ---------------------------------------------------------------- all casts in one launch
// id ranges:
//   [0,2048):      W1 [2048][1024] -> W1T [1024][2048] (transpose)
//   [2048,2560):   W2 [300][1024]  -> W2T [1024][512]  (transpose, zero-pad k)
//   [2560,4128):   x1 [1568][2048] f32 -> x1b bf16 (row cast)
//   [4128,4768):   x2 [640][300]   f32 -> x2b [640][512] bf16 (row cast, pad)
__global__ __launch_bounds__(256) void tcast_all(const float* __restrict__ W1,
                                                 const float* __restrict__ W2,
                                                 const float* __restrict__ x1,
                                                 const float* __restrict__ x2,
                                                 unsigned short* __restrict__ W1T,
                                                 unsigned short* __restrict__ W2T,
                                                 unsigned short* __restrict__ x1b,
                                                 unsigned short* __restrict__ x2b) {
    const int tid = threadIdx.x;
    int id = blockIdx.x;
    if (id < 2560) {                        // transpose paths
        __shared__ unsigned short tile[32][34];
        const float* in;
        unsigned short* out;
        int Ksrc, Kpad, k0, n0;
        if (id < 2048) {                    // W1: 64 k-blocks x 32 n-blocks
            in = W1; out = W1T; Ksrc = DIM1; Kpad = DIM1;
            k0 = (id & 63) * 32; n0 = (id >> 6) * 32;
        } else {                            // W2: 16 k-blocks x 32 n-blocks
            id -= 2048;
            in = W2; out = W2T; Ksrc = DIM2; Kpad = 512;
            k0 = (id & 15) * 32; n0 = (id >> 4) * 32;
        }
        const int tx = tid & 31, ty = tid >> 5;   // 32 x 8
#pragma unroll
        for (int i = 0; i < 4; ++i) {
            const int r = k0 + ty + i * 8;
            const float v = (r < Ksrc) ? in[(size_t)r * 1024 + n0 + tx] : 0.f;
            tile[ty + i * 8][tx] = f2bf(v);
        }
        __syncthreads();
#pragma unroll
        for (int i = 0; i < 4; ++i) {
            const int n = ty + i * 8;
            out[(size_t)(n0 + n) * Kpad + k0 + tx] = tile[tx][n];
        }
    } else if (id < 4128) {                 // x1 row cast: 2048 elems/row
        const int row = id - 2560;
        const float* ip = x1 + (size_t)row * DIM1 + tid * 8;
        const float4 u0 = *reinterpret_cast<const float4*>(ip);
        const float4 u1 = *reinterpret_cast<const float4*>(ip + 4);
        short8_t h;
        h[0] = (short)f2bf(u0.x); h[1] = (short)f2bf(u0.y);
        h[2] = (short)f2bf(u0.z); h[3] = (short)f2bf(u0.w);
        h[4] = (short)f2bf(u1.x); h[5] = (short)f2bf(u1.y);
        h[6] = (short)f2bf(u1.z); h[7] = (short)f2bf(u1.w);
        *reinterpret_cast<short8_t*>(x1b + (size_t)row * DIM1 + tid * 8) = h;
    } else {                                // x2 row cast: 512 elems/row (300 data)
        const int row = id - 4128;
        const int k = tid * 2;
        float2 v = make_float2(0.f, 0.f);
        if (k < DIM2) v = *reinterpret_cast<const float2*>(x2 + (size_t)row * DIM2 + k);
        unsigned short* op = x2b + (size_t)row * 512 + k;
        op[0] = f2bf(v.x);
        op[1] = f2bf(v.y);
    }
}

// ---------------------------------------------------------------- bf16 MFMA GEMM, depth-2 pipelined
// C[M][1024](bf16) = A[M][KPAD](bf16) @ Bt[1024][KPAD](bf16)^T.
// 64x64 tile, BK=128 (NT=KPAD/128, must be even), 4 waves (32x32 each).
// Two named register sets (sA/sB) give prefetch distance 2: LOAD(t+2) is
// consumed two compute-phases later (~600cyc coverage of HBM/L2 latency);
// compiler emits counted vmcnt per set. LDS 2x(16K A + 16K B) = 64KB,
// 256B row pitch, XOR swizzle byte^=((row&7)<<4): writes 2-way (free),
// fragment reads conflict-free per 16-lane phase (verified per-phase math,
// matches measured SQ_LDS_BANK_CONFLICT=0 of the BK=64 predecessor).
template<int KPAD>
__global__ __launch_bounds__(256) void gemm_bf16(const unsigned short* __restrict__ A,
                                                 const unsigned short* __restrict__ Bt,
                                                 unsigned short* __restrict__ C,
                                                 int M) {
    constexpr int NT = KPAD / 128;
    __shared__ __align__(16) char smem[65536];   // [buf][A 16K | B 16K]
    const int tid  = threadIdx.x;
    const int lane = tid & 63;
    const int wave = tid >> 6;
    const int wm = (wave >> 1) * 32;
    const int wn = (wave & 1) * 32;
    const int m0 = blockIdx.y * 64;
    const int n0 = blockIdx.x * 64;

    const int row = tid >> 2;            // 0..63 staging row
    const int kc  = (tid & 3) * 32;      // k element offset within BK
    const int swz = (row & 7) << 4;
    const int sb  = row * 256 + kc * 2;  // staging byte base (pre-XOR)
    const int gm  = m0 + row;
    const bool mv = (gm < M);

    const unsigned short* ap = A  + (size_t)(mv ? gm : 0) * KPAD + kc;
    const unsigned short* bp = Bt + (size_t)(n0 + row) * KPAD + kc;

    short8_t raA[4], rbA[4];             // set A
    short8_t raB[4], rbB[4];             // set B

#define LOADSET(ra, rb, t)                                                   \
    {                                                                        \
        const int k0 = (t) * 128;                                            \
        _Pragma("unroll")                                                    \
        for (int j = 0; j < 4; ++j) {                                        \
            ra[j] = mv ? *reinterpret_cast<const short8_t*>(ap + k0 + j * 8) \
                       : short8_t{0,0,0,0,0,0,0,0};                          \
            rb[j] = *reinterpret_cast<const short8_t*>(bp + k0 + j * 8);     \
        }                                                                    \
    }

#define WRITESET(ra, rb, buf)                                                \
    {                                                                        \
        char* smA = smem + (buf) * 32768;                                    \
        char* smB = smA + 16384;                                             \
        _Pragma("unroll")                                                    \
        for (int j = 0; j < 4; ++j) {                                        \
            *reinterpret_cast<short8_t*>(smA + ((sb + 16 * j) ^ swz)) = ra[j]; \
            *reinterpret_cast<short8_t*>(smB + ((sb + 16 * j) ^ swz)) = rb[j]; \
        }                                                                    \
    }

    f32x4_t acc[2][2] = {};
    const int hi16 = (lane >> 4) << 4;   // frag k-subgroup byte offset
    const int fl   = lane & 15;

#define COMPUTE(buf)                                                         \
    {                                                                        \
        const char* smA = smem + (buf) * 32768;                              \
        const char* smB = smA + 16384;                                       \
        _Pragma("unroll")                                                    \
        for (int kk = 0; kk < 4; ++kk) {                                     \
            short8_t af[2], bf[2];                                           \
            _Pragma("unroll")                                                \
            for (int i = 0; i < 2; ++i) {                                    \
                const int r = wm + i * 16 + fl;                              \
                af[i] = *reinterpret_cast<const short8_t*>(                  \
                    smA + ((r * 256 + kk * 64 + hi16) ^ ((r & 7) << 4)));    \
            }                                                                \
            _Pragma("unroll")                                                \
            for (int j = 0; j < 2; ++j) {                                    \
                const int r = wn + j * 16 + fl;                              \
                bf[j] = *reinterpret_cast<const short8_t*>(                  \
                    smB + ((r * 256 + kk * 64 + hi16) ^ ((r & 7) << 4)));    \
            }                                                                \
            _Pragma("unroll")                                                \
            for (int i = 0; i < 2; ++i)                                      \
                _Pragma("unroll")                                            \
                for (int j = 0; j < 2; ++j)                                  \
                    acc[i][j] = __builtin_amdgcn_mfma_f32_16x16x32_bf16(     \
                        af[i], bf[j], acc[i][j], 0, 0, 0);                   \
        }                                                                    \
    }

    LOADSET(raA, rbA, 0);
    LOADSET(raB, rbB, 1);
    for (int tp = 0; tp < NT; tp += 2) {
        WRITESET(raA, rbA, 0);           // waits set-A loads only (counted vmcnt)
        __syncthreads();
        if (tp + 2 < NT) LOADSET(raA, rbA, tp + 2);
        COMPUTE(0);
        __syncthreads();
        WRITESET(raB, rbB, 1);
        __syncthreads();
        if (tp + 3 < NT) LOADSET(raB, rbB, tp + 3);
        COMPUTE(1);
        __syncthreads();
    }
#undef LOADSET
#undef WRITESET
#undef COMPUTE

    // epilogue: C/D layout col=lane&15, row=(lane>>4)*4+q
#pragma unroll
    for (int i = 0; i < 2; ++i) {
        const int gmb = m0 + wm + i * 16 + ((lane >> 4) << 2);
#pragma unroll
        for (int j = 0; j < 2; ++j) {
            const int gn = n0 + wn + j * 16 + fl;
#pragma unroll
            for (int q = 0; q < 4; ++q) {
                const int gmq = gmb + q;
                if (gmq < M) C[(size_t)gmq * 1024 + gn] = f2bf(acc[i][j][q]);
            }
        }
    }
}

// ---------------------------------------------------------------- score (p-split x4)
// score = bias2 - 2 * sum_a w[a] * rcp(exp2(C * a1 * a2) + 1),  C = 2*log2(e)
// Packed bf16->f32: each u32 holds 2 bf16; lo = u<<16, hi = u&0xffff0000.
__global__ __launch_bounds__(256) void score_part(const unsigned short* __restrict__ a1b,
                                                  const unsigned short* __restrict__ a2b,
                                                  const float* __restrict__ w,
                                                  const float* __restrict__ biasp,
                                                  float* __restrict__ scb) {
    __shared__ float2 aw[ATT];
    const int tid  = threadIdx.x;
    const int lane = tid & 63;
    const int wave = tid >> 6;
    const int b    = blockIdx.x & 7;      // batch -> XCD (L2 residency of a1 slice)
    const int rest = blockIdx.x >> 3;     // 0..319
    const int l    = rest >> 2;
    const int qtr  = rest & 3;
    const float bias2 = biasp[1];

    const unsigned short* a2p = a2b + (size_t)(b * L_ + l) * ATT;
    for (int i = tid; i < ATT; i += 256) {
        const float a2v = bf2f(a2p[i]);
        const int li = i & 511;
        const int phi = (i & ~511) | (((li & 7) << 6) + (li >> 3));
        aw[phi] = make_float2(a2v * 2.885390082f, w[i]);   // 2*log2(e)
    }
    __syncthreads();

    const int base = qtr * 49;
    float* scp = scb + (size_t)(b * L_ + l) * P_;

    for (int g = wave; g < 13; g += 4) {          // 13 groups of 4 rows (last partial)
        const int p0 = base + g * 4;
        int r[4];
#pragma unroll
        for (int q = 0; q < 4; ++q) r[q] = min(p0 + q, P_ - 1);
        float acc[4] = {0.f, 0.f, 0.f, 0.f};
#pragma unroll
        for (int it = 0; it < 2; ++it) {
            uint4 v[4];
#pragma unroll
            for (int q = 0; q < 4; ++q)
                v[q] = *reinterpret_cast<const uint4*>(
                    a1b + (size_t)(b * P_ + r[q]) * ATT + it * 512 + lane * 8);
#pragma unroll
            for (int h = 0; h < 4; ++h) {         // u32 pair index (elems 2h, 2h+1)
                const float2 c0 = aw[it * 512 + (2 * h + 0) * 64 + lane];
                const float2 c1 = aw[it * 512 + (2 * h + 1) * 64 + lane];
#pragma unroll
                for (int q = 0; q < 4; ++q) {
                    const unsigned int u = (&v[q].x)[h];
                    const float flo = __uint_as_float(u << 16);
                    const float fhi = __uint_as_float(u & 0xffff0000u);
                    const float elo = __builtin_amdgcn_exp2f(flo * c0.x);
                    acc[q] = fmaf(c0.y, __builtin_amdgcn_rcpf(elo + 1.0f), acc[q]);
                    const float ehi = __builtin_amdgcn_exp2f(fhi * c1.x);
                    acc[q] = fmaf(c1.y, __builtin_amdgcn_rcpf(ehi + 1.0f), acc[q]);
                }
            }
        }
#pragma unroll
        for (int o = 32; o >= 1; o >>= 1) {
#pragma unroll
            for (int q = 0; q < 4; ++q) acc[q] += __shfl_xor(acc[q], o);
        }
        if (lane < 4) {
            const int p = p0 + lane;
            if (p < base + 49) scp[p] = bias2 - 2.0f * acc[lane];
        }
    }
}

// ---------------------------------------------------------------- fused softmax + label_repr
__global__ __launch_bounds__(256) void label_fused(const float* __restrict__ scb,
                                                   const float* __restrict__ x1,
                                                   float* __restrict__ alpha,
                                                   float* __restrict__ out) {
    __shared__ float al[P_][4];
    const int tid  = threadIdx.x;
    const int lane = tid & 63;
    const int wave = tid >> 6;
    const int id   = blockIdx.x;
    const int b    = id & 7;
    const int rest = id >> 3;           // 0..79
    const int dtile = rest & 3;
    const int l0    = (rest >> 2) * 4;  // 0..76
    const int d0    = dtile * 512;
    const int row   = b * L_ + l0 + wave;

    // --- softmax of row (one wave per l-row)
    const float* sp = scb + (size_t)row * P_;
    float v[4];
#pragma unroll
    for (int k = 0; k < 4; ++k) {
        const int p = lane + k * 64;
        v[k] = (p < P_) ? sp[p] : -INFINITY;
    }
    float m = fmaxf(fmaxf(v[0], v[1]), fmaxf(v[2], v[3]));
#pragma unroll
    for (int o = 32; o >= 1; o >>= 1) m = fmaxf(m, __shfl_xor(m, o));
    float e[4];
    float s = 0.f;
#pragma unroll
    for (int k = 0; k < 4; ++k) {
        const int p = lane + k * 64;
        e[k] = (p < P_) ? __expf(v[k] - m) : 0.f;
        s += e[k];
    }
#pragma unroll
    for (int o = 32; o >= 1; o >>= 1) s += __shfl_xor(s, o);
    const float inv = 1.0f / s;
    float* ap = alpha + (size_t)row * P_;
#pragma unroll
    for (int k = 0; k < 4; ++k) {
        const int p = lane + k * 64;
        if (p < P_) {
            const float a = e[k] * inv;
            al[p][wave] = a;
            if (dtile == 0) ap[p] = a;
        }
    }
    __syncthreads();

    // --- GEMV: out[b, l0..l0+3, d0..d0+511] = alpha @ x1
    const int d = d0 + tid * 2;
    float acc[4][2] = {};
    for (int p = 0; p < P_; ++p) {
        const float2 x = *reinterpret_cast<const float2*>(x1 + ((size_t)(b * P_ + p)) * DIM1 + d);
        const float4 a4 = *reinterpret_cast<const float4*>(&al[p][0]);
        acc[0][0] = fmaf(a4.x, x.x, acc[0][0]);
        acc[0][1] = fmaf(a4.x, x.y, acc[0][1]);
        acc[1][0] = fmaf(a4.y, x.x, acc[1][0]);
        acc[1][1] = fmaf(a4.y, x.y, acc[1][1]);
        acc[2][0] = fmaf(a4.z, x.x, acc[2][0]);
        acc[2][1] = fmaf(a4.z, x.y, acc[2][1]);
        acc[3][0] = fmaf(a4.w, x.x, acc[3][0]);
        acc[3][1] = fmaf(a4.w, x.y, acc[3][1]);
    }
#pragma unroll
    for (int l = 0; l < 4; ++l) {
        float* op = out + ((size_t)(b * L_ + l0 + l)) * DIM1 + d;
        *reinterpret_cast<float2*>(op) = make_float2(acc[l][0], acc[l][1]);
    }
}

// ---------------------------------------------------------------- launch
extern "C" void kernel_launch(void* const* d_in, const int* in_sizes, int n_in,
                              void* d_out, int out_size, void* d_ws, size_t ws_size,
                              hipStream_t stream) {
    const float* x1 = (const float*)d_in[0];
    const float* x2 = (const float*)d_in[1];
    const float* W1 = (const float*)d_in[2];
    const float* W2 = (const float*)d_in[3];
    const float* Wh = (const float*)d_in[4];
    const float* bh = (const float*)d_in[5];
    const float* Wt = (const float*)d_in[6];
    const float* bt = (const float*)d_in[7];

    float* out       = (float*)d_out;
    float* label_out = out;                                  // B*L*DIM1
    float* alpha_out = out + (size_t)B_ * L_ * DIM1;         // B*L*P

    // workspace layout (ushort offsets); ws_size ~268MB, ~17MB used
    unsigned short* usw = (unsigned short*)d_ws;
    unsigned short* W1T = usw;                         // 1024*2048 = 2097152
    unsigned short* W2T = usw + 2097152;               // 1024*512  = 524288
    unsigned short* x1b = usw + 2621440;               // 1568*2048 = 3211264
    unsigned short* a1b = usw + 5832704;               // 1568*1024 = 1605632
    unsigned short* x2b = usw + 7438336;               // 640*512   = 327680
    unsigned short* a2b = usw + 7766016;               // 640*1024  = 655360
    float* wv    = (float*)(usw + 8421376);            // 1024
    float* biasv = wv + 1024;                          // 2
    float* scb   = wv + 1028;                          // 640*196 raw scores

    hipMemsetAsync(biasv, 0, 2 * sizeof(float), stream);

    prep_w<<<ATT / 4 + 1, 256, 0, stream>>>(Wh, bh, Wt, bt, wv, biasv);

    tcast_all<<<4768, 256, 0, stream>>>(W1, W2, x1, x2, W1T, W2T, x1b, x2b);

    gemm_bf16<DIM1><<<dim3(16, 25), 256, 0, stream>>>(x1b, W1T, a1b, B_ * P_);
    gemm_bf16<512><<<dim3(16, 10), 256, 0, stream>>>(x2b, W2T, a2b, B_ * L_);

    score_part<<<B_ * L_ * 4, 256, 0, stream>>>(a1b, a2b, wv, biasv, scb);

    label_fused<<<B_ * L_ * 4 / 4, 256, 0, stream>>>(scb, x1, alpha_out, label_out);
}

// Round 11
// 177.416 us; speedup vs baseline: 1.1135x; 1.0989x over previous
//
#include <hip/hip_runtime.h>
#include <math.h>

#define B_   8
#define P_   196
#define L_   80
#define DIM1 2048
#define DIM2 300
#define ATT  1024

typedef __attribute__((ext_vector_type(8))) short short8_t;
typedef __attribute__((ext_vector_type(4))) float f32x4_t;

__device__ inline unsigned short f2bf(float f) {
    unsigned int u = __float_as_uint(f);
    u += 0x7fff + ((u >> 16) & 1);          // RNE
    return (unsigned short)(u >> 16);
}
__device__ inline float bf2f(unsigned short h) {
    return __uint_as_float(((unsigned int)h) << 16);
}

// ---------------------------------------------------------------- merged prep:
// blocks [0,256):        w = Wh@Wt (4 rows/block, one wave each)
// blocks [256,2816):     W1/W2 transpose+cast (bias term is DROPPED: softmax
//                        is shift-invariant, bias2 is constant over p, and
//                        neither output depends on it)
// blocks [2816,4384):    x1 f32 -> bf16 row cast
// blocks [4384,5024):    x2 f32 -> bf16 row cast (pad 300->512)
__global__ __launch_bounds__(256) void prep_tcast(const float* __restrict__ Wh,
                                                  const float* __restrict__ Wt,
                                                  const float* __restrict__ W1,
                                                  const float* __restrict__ W2,
                                                  const float* __restrict__ x1,
                                                  const float* __restrict__ x2,
                                                  float* __restrict__ w,
                                                  unsigned short* __restrict__ W1T,
                                                  unsigned short* __restrict__ W2T,
                                                  unsigned short* __restrict__ x1b,
                                                  unsigned short* __restrict__ x2b) {
    __shared__ unsigned short tile[32][34];
    const int tid = threadIdx.x;
    int id = blockIdx.x;
    if (id < 256) {                         // w = Wh @ Wt
        const int lane = tid & 63;
        const int row  = id * 4 + (tid >> 6);
        const float* src = Wh + (size_t)row * ATT;
        float acc = 0.0f;
#pragma unroll
        for (int it = 0; it < ATT / 256; ++it) {
            const int i = it * 256 + lane * 4;
            const float4 a = *reinterpret_cast<const float4*>(src + i);
            const float4 b = *reinterpret_cast<const float4*>(Wt + i);
            acc = fmaf(a.x, b.x, acc);
            acc = fmaf(a.y, b.y, acc);
            acc = fmaf(a.z, b.z, acc);
            acc = fmaf(a.w, b.w, acc);
        }
#pragma unroll
        for (int o = 32; o >= 1; o >>= 1) acc += __shfl_xor(acc, o);
        if (lane == 0) w[row] = acc;
        return;
    }
    id -= 256;
    if (id < 2560) {                        // transpose paths
        const float* in;
        unsigned short* out;
        int Ksrc, Kpad, k0, n0;
        if (id < 2048) {                    // W1: 64 k-blocks x 32 n-blocks
            in = W1; out = W1T; Ksrc = DIM1; Kpad = DIM1;
            k0 = (id & 63) * 32; n0 = (id >> 6) * 32;
        } else {                            // W2: 16 k-blocks x 32 n-blocks
            id -= 2048;
            in = W2; out = W2T; Ksrc = DIM2; Kpad = 512;
            k0 = (id & 15) * 32; n0 = (id >> 4) * 32;
        }
        const int tx = tid & 31, ty = tid >> 5;   // 32 x 8
#pragma unroll
        for (int i = 0; i < 4; ++i) {
            const int r = k0 + ty + i * 8;
            const float v = (r < Ksrc) ? in[(size_t)r * 1024 + n0 + tx] : 0.f;
            tile[ty + i * 8][tx] = f2bf(v);
        }
        __syncthreads();
#pragma unroll
        for (int i = 0; i < 4; ++i) {
            const int n = ty + i * 8;
            out[(size_t)(n0 + n) * Kpad + k0 + tx] = tile[tx][n];
        }
    } else if (id < 4128) {                 // x1 row cast: 2048 elems/row
        const int row = id - 2560;
        const float* ip = x1 + (size_t)row * DIM1 + tid * 8;
        const float4 u0 = *reinterpret_cast<const float4*>(ip);
        const float4 u1 = *reinterpret_cast<const float4*>(ip + 4);
        short8_t h;
        h[0] = (short)f2bf(u0.x); h[1] = (short)f2bf(u0.y);
        h[2] = (short)f2bf(u0.z); h[3] = (short)f2bf(u0.w);
        h[4] = (short)f2bf(u1.x); h[5] = (short)f2bf(u1.y);
        h[6] = (short)f2bf(u1.z); h[7] = (short)f2bf(u1.w);
        *reinterpret_cast<short8_t*>(x1b + (size_t)row * DIM1 + tid * 8) = h;
    } else {                                // x2 row cast: 512 elems/row (300 data)
        const int row = id - 4128;
        const int k = tid * 2;
        float2 v = make_float2(0.f, 0.f);
        if (k < DIM2) v = *reinterpret_cast<const float2*>(x2 + (size_t)row * DIM2 + k);
        unsigned short* op = x2b + (size_t)row * 512 + k;
        op[0] = f2bf(v.x);
        op[1] = f2bf(v.y);
    }
}

// ---------------------------------------------------------------- bf16 MFMA GEMM, depth-2 pipelined
// C[M][1024](bf16) = A[M][KPAD](bf16) @ Bt[1024][KPAD](bf16)^T.
// 64x64 tile, BK=128 (NT=KPAD/128, must be even), 4 waves (32x32 each).
// Two named register sets give prefetch distance 2 (~600cyc latency cover);
// compiler emits counted vmcnt per set. LDS 2x(16K A + 16K B) = 64KB,
// 256B row pitch, XOR swizzle byte^=((row&7)<<4).
template<int KPAD>
__global__ __launch_bounds__(256) void gemm_bf16(const unsigned short* __restrict__ A,
                                                 const unsigned short* __restrict__ Bt,
                                                 unsigned short* __restrict__ C,
                                                 int M) {
    constexpr int NT = KPAD / 128;
    __shared__ __align__(16) char smem[65536];   // [buf][A 16K | B 16K]
    const int tid  = threadIdx.x;
    const int lane = tid & 63;
    const int wave = tid >> 6;
    const int wm = (wave >> 1) * 32;
    const int wn = (wave & 1) * 32;
    const int m0 = blockIdx.y * 64;
    const int n0 = blockIdx.x * 64;

    const int row = tid >> 2;            // 0..63 staging row
    const int kc  = (tid & 3) * 32;      // k element offset within BK
    const int swz = (row & 7) << 4;
    const int sb  = row * 256 + kc * 2;  // staging byte base (pre-XOR)
    const int gm  = m0 + row;
    const bool mv = (gm < M);

    const unsigned short* ap = A  + (size_t)(mv ? gm : 0) * KPAD + kc;
    const unsigned short* bp = Bt + (size_t)(n0 + row) * KPAD + kc;

    short8_t raA[4], rbA[4];             // set A
    short8_t raB[4], rbB[4];             // set B

#define LOADSET(ra, rb, t)                                                   \
    {                                                                        \
        const int k0 = (t) * 128;                                            \
        _Pragma("unroll")                                                    \
        for (int j = 0; j < 4; ++j) {                                        \
            ra[j] = mv ? *reinterpret_cast<const short8_t*>(ap + k0 + j * 8) \
                       : short8_t{0,0,0,0,0,0,0,0};                          \
            rb[j] = *reinterpret_cast<const short8_t*>(bp + k0 + j * 8);     \
        }                                                                    \
    }

#define WRITESET(ra, rb, buf)                                                \
    {                                                                        \
        char* smA = smem + (buf) * 32768;                                    \
        char* smB = smA + 16384;                                             \
        _Pragma("unroll")                                                    \
        for (int j = 0; j < 4; ++j) {                                        \
            *reinterpret_cast<short8_t*>(smA + ((sb + 16 * j) ^ swz)) = ra[j]; \
            *reinterpret_cast<short8_t*>(smB + ((sb + 16 * j) ^ swz)) = rb[j]; \
        }                                                                    \
    }

    f32x4_t acc[2][2] = {};
    const int hi16 = (lane >> 4) << 4;   // frag k-subgroup byte offset
    const int fl   = lane & 15;

#define COMPUTE(buf)                                                         \
    {                                                                        \
        const char* smA = smem + (buf) * 32768;                              \
        const char* smB = smA + 16384;                                       \
        _Pragma("unroll")                                                    \
        for (int kk = 0; kk < 4; ++kk) {                                     \
            short8_t af[2], bf[2];                                           \
            _Pragma("unroll")                                                \
            for (int i = 0; i < 2; ++i) {                                    \
                const int r = wm + i * 16 + fl;                              \
                af[i] = *reinterpret_cast<const short8_t*>(                  \
                    smA + ((r * 256 + kk * 64 + hi16) ^ ((r & 7) << 4)));    \
            }                                                                \
            _Pragma("unroll")                                                \
            for (int j = 0; j < 2; ++j) {                                    \
                const int r = wn + j * 16 + fl;                              \
                bf[j] = *reinterpret_cast<const short8_t*>(                  \
                    smB + ((r * 256 + kk * 64 + hi16) ^ ((r & 7) << 4)));    \
            }                                                                \
            _Pragma("unroll")                                                \
            for (int i = 0; i < 2; ++i)                                      \
                _Pragma("unroll")                                            \
                for (int j = 0; j < 2; ++j)                                  \
                    acc[i][j] = __builtin_amdgcn_mfma_f32_16x16x32_bf16(     \
                        af[i], bf[j], acc[i][j], 0, 0, 0);                   \
        }                                                                    \
    }

    LOADSET(raA, rbA, 0);
    LOADSET(raB, rbB, 1);
    for (int tp = 0; tp < NT; tp += 2) {
        WRITESET(raA, rbA, 0);           // waits set-A loads only (counted vmcnt)
        __syncthreads();
        if (tp + 2 < NT) LOADSET(raA, rbA, tp + 2);
        COMPUTE(0);
        __syncthreads();
        WRITESET(raB, rbB, 1);
        __syncthreads();
        if (tp + 3 < NT) LOADSET(raB, rbB, tp + 3);
        COMPUTE(1);
        __syncthreads();
    }
#undef LOADSET
#undef WRITESET
#undef COMPUTE

    // epilogue: C/D layout col=lane&15, row=(lane>>4)*4+q
#pragma unroll
    for (int i = 0; i < 2; ++i) {
        const int gmb = m0 + wm + i * 16 + ((lane >> 4) << 2);
#pragma unroll
        for (int j = 0; j < 2; ++j) {
            const int gn = n0 + wn + j * 16 + fl;
#pragma unroll
            for (int q = 0; q < 4; ++q) {
                const int gmq = gmb + q;
                if (gmq < M) C[(size_t)gmq * 1024 + gn] = f2bf(acc[i][j][q]);
            }
        }
    }
}

// ---------------------------------------------------------------- score (p-split x4)
// score = -2 * sum_a w[a] * rcp(exp2(C * a1 * a2) + 1)   [+const, dropped:
// softmax is shift-invariant and nothing else consumes the score]
// Packed bf16->f32: each u32 holds 2 bf16; lo = u<<16, hi = u&0xffff0000.
__global__ __launch_bounds__(256) void score_part(const unsigned short* __restrict__ a1b,
                                                  const unsigned short* __restrict__ a2b,
                                                  const float* __restrict__ w,
                                                  float* __restrict__ scb) {
    __shared__ float2 aw[ATT];
    const int tid  = threadIdx.x;
    const int lane = tid & 63;
    const int wave = tid >> 6;
    const int b    = blockIdx.x & 7;      // batch -> XCD (L2 residency of a1 slice)
    const int rest = blockIdx.x >> 3;     // 0..319
    const int l    = rest >> 2;
    const int qtr  = rest & 3;

    const unsigned short* a2p = a2b + (size_t)(b * L_ + l) * ATT;
    for (int i = tid; i < ATT; i += 256) {
        const float a2v = bf2f(a2p[i]);
        const int li = i & 511;
        const int phi = (i & ~511) | (((li & 7) << 6) + (li >> 3));
        aw[phi] = make_float2(a2v * 2.885390082f, w[i]);   // 2*log2(e)
    }
    __syncthreads();

    const int base = qtr * 49;
    float* scp = scb + (size_t)(b * L_ + l) * P_;

    for (int g = wave; g < 13; g += 4) {          // 13 groups of 4 rows (last partial)
        const int p0 = base + g * 4;
        int r[4];
#pragma unroll
        for (int q = 0; q < 4; ++q) r[q] = min(p0 + q, P_ - 1);
        float acc[4] = {0.f, 0.f, 0.f, 0.f};
#pragma unroll
        for (int it = 0; it < 2; ++it) {
            uint4 v[4];
#pragma unroll
            for (int q = 0; q < 4; ++q)
                v[q] = *reinterpret_cast<const uint4*>(
                    a1b + (size_t)(b * P_ + r[q]) * ATT + it * 512 + lane * 8);
#pragma unroll
            for (int h = 0; h < 4; ++h) {         // u32 pair index (elems 2h, 2h+1)
                const float2 c0 = aw[it * 512 + (2 * h + 0) * 64 + lane];
                const float2 c1 = aw[it * 512 + (2 * h + 1) * 64 + lane];
#pragma unroll
                for (int q = 0; q < 4; ++q) {
                    const unsigned int u = (&v[q].x)[h];
                    const float flo = __uint_as_float(u << 16);
                    const float fhi = __uint_as_float(u & 0xffff0000u);
                    const float elo = __builtin_amdgcn_exp2f(flo * c0.x);
                    acc[q] = fmaf(c0.y, __builtin_amdgcn_rcpf(elo + 1.0f), acc[q]);
                    const float ehi = __builtin_amdgcn_exp2f(fhi * c1.x);
                    acc[q] = fmaf(c1.y, __builtin_amdgcn_rcpf(ehi + 1.0f), acc[q]);
                }
            }
        }
#pragma unroll
        for (int o = 32; o >= 1; o >>= 1) {
#pragma unroll
            for (int q = 0; q < 4; ++q) acc[q] += __shfl_xor(acc[q], o);
        }
        if (lane < 4) {
            const int p = p0 + lane;
            if (p < base + 49) scp[p] = -2.0f * acc[lane];
        }
    }
}

// ---------------------------------------------------------------- fused softmax + label_repr
__global__ __launch_bounds__(256) void label_fused(const float* __restrict__ scb,
                                                   const float* __restrict__ x1,
                                                   float* __restrict__ alpha,
                                                   float* __restrict__ out) {
    __shared__ float al[P_][4];
    const int tid  = threadIdx.x;
    const int lane = tid & 63;
    const int wave = tid >> 6;
    const int id   = blockIdx.x;
    const int b    = id & 7;
    const int rest = id >> 3;           // 0..79
    const int dtile = rest & 3;
    const int l0    = (rest >> 2) * 4;  // 0..76
    const int d0    = dtile * 512;
    const int row   = b * L_ + l0 + wave;

    // --- softmax of row (one wave per l-row)
    const float* sp = scb + (size_t)row * P_;
    float v[4];
#pragma unroll
    for (int k = 0; k < 4; ++k) {
        const int p = lane + k * 64;
        v[k] = (p < P_) ? sp[p] : -INFINITY;
    }
    float m = fmaxf(fmaxf(v[0], v[1]), fmaxf(v[2], v[3]));
#pragma unroll
    for (int o = 32; o >= 1; o >>= 1) m = fmaxf(m, __shfl_xor(m, o));
    float e[4];
    float s = 0.f;
#pragma unroll
    for (int k = 0; k < 4; ++k) {
        const int p = lane + k * 64;
        e[k] = (p < P_) ? __expf(v[k] - m) : 0.f;
        s += e[k];
    }
#pragma unroll
    for (int o = 32; o >= 1; o >>= 1) s += __shfl_xor(s, o);
    const float inv = 1.0f / s;
    float* ap = alpha + (size_t)row * P_;
#pragma unroll
    for (int k = 0; k < 4; ++k) {
        const int p = lane + k * 64;
        if (p < P_) {
            const float a = e[k] * inv;
            al[p][wave] = a;
            if (dtile == 0) ap[p] = a;
        }
    }
    __syncthreads();

    // --- GEMV: out[b, l0..l0+3, d0..d0+511] = alpha @ x1
    const int d = d0 + tid * 2;
    float acc[4][2] = {};
    for (int p = 0; p < P_; ++p) {
        const float2 x = *reinterpret_cast<const float2*>(x1 + ((size_t)(b * P_ + p)) * DIM1 + d);
        const float4 a4 = *reinterpret_cast<const float4*>(&al[p][0]);
        acc[0][0] = fmaf(a4.x, x.x, acc[0][0]);
        acc[0][1] = fmaf(a4.x, x.y, acc[0][1]);
        acc[1][0] = fmaf(a4.y, x.x, acc[1][0]);
        acc[1][1] = fmaf(a4.y, x.y, acc[1][1]);
        acc[2][0] = fmaf(a4.z, x.x, acc[2][0]);
        acc[2][1] = fmaf(a4.z, x.y, acc[2][1]);
        acc[3][0] = fmaf(a4.w, x.x, acc[3][0]);
        acc[3][1] = fmaf(a4.w, x.y, acc[3][1]);
    }
#pragma unroll
    for (int l = 0; l < 4; ++l) {
        float* op = out + ((size_t)(b * L_ + l0 + l)) * DIM1 + d;
        *reinterpret_cast<float2*>(op) = make_float2(acc[l][0], acc[l][1]);
    }
}

// ---------------------------------------------------------------- launch
extern "C" void kernel_launch(void* const* d_in, const int* in_sizes, int n_in,
                              void* d_out, int out_size, void* d_ws, size_t ws_size,
                              hipStream_t stream) {
    const float* x1 = (const float*)d_in[0];
    const float* x2 = (const float*)d_in[1];
    const float* W1 = (const float*)d_in[2];
    const float* W2 = (const float*)d_in[3];
    const float* Wh = (const float*)d_in[4];
    const float* Wt = (const float*)d_in[6];

    float* out       = (float*)d_out;
    float* label_out = out;                                  // B*L*DIM1
    float* alpha_out = out + (size_t)B_ * L_ * DIM1;         // B*L*P

    // workspace layout (ushort offsets); ws_size ~268MB, ~17MB used
    unsigned short* usw = (unsigned short*)d_ws;
    unsigned short* W1T = usw;                         // 1024*2048 = 2097152
    unsigned short* W2T = usw + 2097152;               // 1024*512  = 524288
    unsigned short* x1b = usw + 2621440;               // 1568*2048 = 3211264
    unsigned short* a1b = usw + 5832704;               // 1568*1024 = 1605632
    unsigned short* x2b = usw + 7438336;               // 640*512   = 327680
    unsigned short* a2b = usw + 7766016;               // 640*1024  = 655360
    float* wv    = (float*)(usw + 8421376);            // 1024
    float* scb   = wv + 1024;                          // 640*196 raw scores

    prep_tcast<<<5024, 256, 0, stream>>>(Wh, Wt, W1, W2, x1, x2,
                                         wv, W1T, W2T, x1b, x2b);

    gemm_bf16<DIM1><<<dim3(16, 25), 256, 0, stream>>>(x1b, W1T, a1b, B_ * P_);
    gemm_bf16<512><<<dim3(16, 10), 256, 0, stream>>>(x2b, W2T, a2b, B_ * L_);

    score_part<<<B_ * L_ * 4, 256, 0, stream>>>(a1b, a2b, wv, scb);

    label_fused<<<B_ * L_ * 4 / 4, 256, 0, stream>>>(scb, x1, alpha_out, label_out);
}